// Round 10
// baseline (134.675 us; speedup 1.0000x reference)
//
#include <hip/hip_runtime.h>
#include <cstdint>
#include <cmath>

#define DEV __device__ __forceinline__

constexpr int SEL = 20;
constexpr int NSTEP2 = 10, NSTEP3 = 22, NSTEPS = 32;
constexpr int L2 = SEL + 1;   // 21 bits, group2
constexpr int L3 = SEL;       // 20 bits, group3
constexpr int H = 4;
constexpr int P = 4;          // Chebyshev probes (deg-3: err ~1e-5 for this near-exp fn)

typedef float v2f __attribute__((ext_vector_type(2)));

// ---- ws layout (float indices) ----
constexpr int OFF_T      = 0;                               // T[2][22][P] = 176
constexpr int OFF_SUMS   = OFF_T + 2 * 22 * P;
constexpr int SUMS_STRIDE = 96;                             // [0]=Se [1]=Sw [2..5]=Sws [6..9]=Swh [10+h*21+d]=GW1
constexpr int OFF_PCHAIN = OFF_SUMS + NSTEPS * SUMS_STRIDE;
constexpr int OFF_KEYB   = OFF_PCHAIN + 40;                 // keybase[32][4]
constexpr int OFF_CT     = OFF_KEYB + 128;                  // int c_t[32]
constexpr int OFF_CB     = OFF_CT + 32;                     // uint chunkbits[32]
constexpr int OFF_NEED   = OFF_CB + 32;                     // uint neededmask[2]
constexpr int WS_FLOATS  = OFF_NEED + 8;

constexpr float K2E = 2.8853900817779268f;   // 2*log2(e)
constexpr float KE  = 1.4426950408889634f;   // log2(e)

// runtime-indexed (kb)
__constant__ float CHEB_P[P] = {0.96193976625f, 0.69134171618f, 0.30865828382f, 0.03806023375f};
__constant__ float CHEB_W[P] = {0.38268343236f, -0.92387953251f, 0.92387953251f, -0.38268343236f};
// compile-time immediates (ka)
constexpr float CHEB_PC[P] = {0.96193976625f, 0.69134171618f, 0.30865828382f, 0.03806023375f};

struct Binom { unsigned v[22][22]; };
constexpr Binom make_binom() {
  Binom b{};
  for (int n = 0; n < 22; n++) {
    b.v[n][0] = 1;
    for (int k = 1; k < 22; k++)
      b.v[n][k] = (k > n) ? 0u : (k == n ? 1u : b.v[n - 1][k - 1] + b.v[n - 1][k]);
  }
  return b;
}
constexpr Binom BN_H = make_binom();
__device__ constexpr Binom BN = make_binom();

DEV float fast_tanh(float x) {
  float e = exp2f(x * K2E);  // e^(2x)
  return 1.0f - 2.0f * __builtin_amdgcn_rcpf(e + 1.0f);
}
DEV float fast_exp(float x) { return exp2f(x * KE); }

// native fp32 atomic (global_atomic_add_f32) — avoids hipcc's default CAS loop
DEV void gatomic(float* p, float v) { unsafeAtomicAdd(p, v); }

DEV unsigned gosper(unsigned cmb) {
  unsigned u = cmb & (~cmb + 1u);
  unsigned v = cmb + u;
  return v | ((cmb ^ v) >> (1 + __ffs(u)));
}

DEV unsigned unrank_lds(const unsigned* sBN, int L, int c, unsigned r) {
  unsigned cmb = 0; int kk = c;
  for (int bb = L - 1; bb >= 0 && kk > 0; bb--) {
    unsigned cnt = sBN[bb * 22 + kk];
    if (r >= cnt) { cmb |= 1u << bb; r -= cnt; kk--; }
  }
  return cmb;
}

constexpr unsigned cdiv_u(unsigned a, unsigned b) { return (a + b - 1) / b; }

DEV float wsum64(float v) {
  for (int m = 1; m < 64; m <<= 1) v += __shfl_xor(v, m);
  return v;
}

// =================== Kernel Z: init / decode chunks ===================
__global__ void kz(const float* p0, const float* sel,
                   const float* W1_2, const float* b1_2,
                   const float* W1_3, const float* b1_3, float* ws) {
  int t = threadIdx.x;
  for (int i = t; i < WS_FLOATS; i += blockDim.x) ws[i] = 0.0f;
  __syncthreads();
  if (t < NSTEPS) {
    int g = (t < NSTEP2) ? 0 : 1;
    int L = g ? L3 : L2;
    const float* sbase = sel + (g ? (NSTEP2 * L2 + (t - NSTEP2) * L3) : t * L2);
    unsigned cb = 0; int c = 0;
    for (int d = 0; d < L; d++)
      if (sbase[d] > 0.5f) { cb |= 1u << d; c++; }
    ((int*)ws)[OFF_CT + t] = c;
    ((unsigned*)ws)[OFF_CB + t] = cb;
    atomicOr(&((unsigned*)ws)[OFF_NEED + g], 1u << c);
    const float* W1 = g ? W1_3 : W1_2;
    const float* b1 = g ? b1_3 : b1_2;
    for (int h = 0; h < H; h++) {
      float s = b1[h];
      for (int d = 0; d < L; d++)
        if ((cb >> d) & 1) s += W1[h * (L + 1) + 1 + d];
      ws[OFF_KEYB + t * 4 + h] = s;
    }
    if (t == 0) ws[OFF_PCHAIN] = p0[0];
  }
}

// =================== Kernel A: per-class tabulation of T[g][c][j], E-trick ===================
constexpr int KA_CPT = 16;
constexpr int KA_RPB = 256 * KA_CPT; // 4096

struct KaOff { int off2[23]; int off3[22]; int total2; int total; };
constexpr KaOff make_kaoff() {
  KaOff o{};
  int cum = 0;
  for (int c = 0; c <= 21; c++) { o.off2[c] = cum; cum += (int)cdiv_u(BN_H.v[21][c], KA_RPB); }
  o.off2[22] = cum; o.total2 = cum;
  int cum3 = 0;
  for (int c = 0; c <= 20; c++) { o.off3[c] = cum3; cum3 += (int)cdiv_u(BN_H.v[20][c], KA_RPB); }
  o.off3[21] = cum3;
  o.total = cum + cum3;
  return o;
}
constexpr KaOff KAOFF = make_kaoff();

// 3 x 128-entry tables of per-7-bit-group partial sums (which==0 holds b1)
template<int LL>
DEV void tab3_setup(const float* W1, const float* b1,
                    float4* tab0, float4* tab1, float4* tab2) {
  int tx = threadIdx.x;
  for (int i = tx; i < 384; i += 256) {
    int which = i >> 7, e = i & 127;
    int lo = which * 7; int nb = (which < 2) ? 7 : (LL - 14);
    float4 v; float* vp = (float*)&v;
    for (int h = 0; h < 4; h++) {
      float s = (which == 0) ? b1[h] : 0.0f;
      for (int j = 0; j < nb; j++)
        if ((e >> j) & 1) s += W1[h * (LL + 1) + 1 + lo + j];
      vp[h] = s;
    }
    if (which == 0) tab0[e] = v; else if (which == 1) tab1[e] = v; else tab2[e] = v;
  }
}

template<int LL>
DEV void ka_work(int g, int c, int sub,
                 const float* W1, const float* b1, const float* W2, const float* b2,
                 float* ws, unsigned* sBN, float4* tab0, float4* tab1, float4* tab2,
                 float* sT) {
  int tx = threadIdx.x;
  const unsigned* bnf = &BN.v[0][0];
  for (int i = tx; i < 484; i += 256) sBN[i] = bnf[i];
  if (tx < P) sT[tx] = 0.0f;
  tab3_setup<LL>(W1, b1, tab0, tab1, tab2);
  __syncthreads();
  float a0 = W1[0], a1 = W1[LL + 1], a2 = W1[2 * (LL + 1)], a3 = W1[3 * (LL + 1)];
  float w0 = W2[0], w1 = W2[1], w2 = W2[2], w3 = W2[3];
  float W0 = b2[0] + w0 + w1 + w2 + w3;
  float m0 = -2.0f * w0, m1 = -2.0f * w1, m2 = -2.0f * w2, m3 = -2.0f * w3;
#define A_DECL(j) \
  const float A##j##_0 = exp2f(K2E * CHEB_PC[j] * a0), A##j##_1 = exp2f(K2E * CHEB_PC[j] * a1), \
              A##j##_2 = exp2f(K2E * CHEB_PC[j] * a2), A##j##_3 = exp2f(K2E * CHEB_PC[j] * a3); \
  float acc##j = 0.0f;
  A_DECL(0) A_DECL(1) A_DECL(2) A_DECL(3)
#undef A_DECL
  unsigned C = BN.v[LL][c];
  unsigned r0 = (unsigned)sub * KA_RPB + (unsigned)tx * KA_CPT;
  int nI = (int)C - (int)r0;
  if (nI > KA_CPT) nI = KA_CPT;
  unsigned cmb = (nI > 0) ? unrank_lds(sBN, LL, c, r0) : 0u;
#pragma unroll 1
  for (int k = 0; k < nI; k++) {
    unsigned n = cmb;
    float4 v0 = tab0[n & 127], v1 = tab1[(n >> 7) & 127], v2 = tab2[(n >> 14) & 127];
    float E0 = exp2f(K2E * (v0.x + v1.x + v2.x));
    float E1 = exp2f(K2E * (v0.y + v1.y + v2.y));
    float E2 = exp2f(K2E * (v0.z + v1.z + v2.z));
    float E3 = exp2f(K2E * (v0.w + v1.w + v2.w));
#define PROBE(j) { \
    float o = W0 + m0 * __builtin_amdgcn_rcpf(fmaf(E0, A##j##_0, 1.0f)) \
                 + m1 * __builtin_amdgcn_rcpf(fmaf(E1, A##j##_1, 1.0f)) \
                 + m2 * __builtin_amdgcn_rcpf(fmaf(E2, A##j##_2, 1.0f)) \
                 + m3 * __builtin_amdgcn_rcpf(fmaf(E3, A##j##_3, 1.0f)); \
    acc##j += exp2f(KE * o); }
    PROBE(0) PROBE(1) PROBE(2) PROBE(3)
#undef PROBE
    cmb = gosper(cmb);
  }
#define FLUSH(j) { \
    float v = wsum64(acc##j); \
    if ((tx & 63) == 0 && v != 0.0f) atomicAdd(&sT[j], v); }
  FLUSH(0) FLUSH(1) FLUSH(2) FLUSH(3)
#undef FLUSH
  __syncthreads();
  if (tx < P) {
    float v = sT[tx];
    if (v != 0.0f) gatomic(&ws[OFF_T + g * 22 * P + c * P + tx], v);
  }
}

__global__ __launch_bounds__(256) void ka(
    const float* W1_2, const float* b1_2, const float* W2_2, const float* b2_2,
    const float* W1_3, const float* b1_3, const float* W2_3, const float* b2_3,
    float* ws) {
  __shared__ unsigned sBN[484];
  __shared__ float4 tab0[128], tab1[128], tab2[128];
  __shared__ float sT[P];
  int b = blockIdx.x;
  int g, c = 0, sub;
  if (b < KAOFF.total2) {
    g = 0;
#pragma unroll
    for (int cc = 1; cc <= 21; cc++) if (b >= KAOFF.off2[cc]) c = cc;
    sub = b - KAOFF.off2[c];
  } else {
    g = 1; int b3 = b - KAOFF.total2;
#pragma unroll
    for (int cc = 1; cc <= 20; cc++) if (b3 >= KAOFF.off3[cc]) c = cc;
    sub = b3 - KAOFF.off3[c];
  }
  unsigned need = ((const unsigned*)ws)[OFF_NEED + g];
  if (!((need >> c) & 1)) return;
  if (g == 0) ka_work<21>(0, c, sub, W1_2, b1_2, W2_2, b2_2, ws, sBN, tab0, tab1, tab2, sT);
  else        ka_work<20>(1, c, sub, W1_3, b1_3, W2_3, b2_3, ws, sBN, tab0, tab1, tab2, sT);
}

// =================== Kernel B: prob chain, 64-lane cooperative ===================
__global__ __launch_bounds__(64) void kb(const float* p0in,
                   const float* W1_2, const float* b1_2, const float* W2_2, const float* b2_2,
                   const float* W1_3, const float* b1_3, const float* W2_3, const float* b2_3,
                   float* ws, float* out) {
  __shared__ float sT[2 * 22 * P];
  __shared__ float sKEYB[128], sW1c0[8], sW2[8], sB2[2];
  __shared__ int sCT[32];
  int lane = threadIdx.x;
  for (int i = lane; i < 2 * 22 * P; i += 64) sT[i] = ws[OFF_T + i];
  for (int i = lane; i < 128; i += 64) sKEYB[i] = ws[OFF_KEYB + i];
  if (lane < 32) sCT[lane] = ((const int*)ws)[OFF_CT + lane];
  if (lane < 4) {
    sW1c0[lane]     = W1_2[lane * (L2 + 1)];
    sW1c0[4 + lane] = W1_3[lane * (L3 + 1)];
    sW2[lane]     = W2_2[lane];
    sW2[4 + lane] = W2_3[lane];
  }
  if (lane == 0) { sB2[0] = b2_2[0]; sB2[1] = b2_3[0]; }
  __syncthreads();
  float p = p0in[0];
  if (lane == 0) out[0] = p;
  int h = lane & 3;   // also the interp node index j
#pragma unroll 1
  for (int tt = 0; tt < NSTEPS; tt++) {
    int g = (tt < NSTEP2) ? 0 : 1;
    int c = sCT[tt];
    float hk = fast_tanh(sKEYB[tt * 4 + h] + p * sW1c0[g * 4 + h]);
    float contrib = sW2[g * 4 + h] * hk;
    contrib += __shfl_xor(contrib, 1);
    contrib += __shfl_xor(contrib, 2);
    float outk = sB2[g] + contrib;
    float Tv = sT[(g * 22 + c) * P + h];
    float d = p - CHEB_P[h];
    float ad = fabsf(d);
    d = (ad < 1e-9f) ? ((d < 0.0f) ? -1e-9f : 1e-9f) : d;
    float q = CHEB_W[h] / d;
    float num = q * Tv, den = q;
    num += __shfl_xor(num, 1); den += __shfl_xor(den, 1);
    num += __shfl_xor(num, 2); den += __shfl_xor(den, 2);
    float Se = num / den;
    p = fast_exp(outk) / Se;
    if (lane == 0) { out[1 + tt] = p; ws[OFF_PCHAIN + 1 + tt] = p; }
  }
}

// =================== Kernel C: balanced rank-sliced enumeration ===================
// combo bits: [0, FB) = enumerated field (FB = L-5); [FB, FB+5) = sub (block-structural).
// Lanes take contiguous equal rank-slices of class C(FB, a) -> zero divergence.
// Grads: field bits 0..7 via register accumulators; bits 8.. via colex run-flush to LDS;
// sub bits via conditional epilogue adds.
constexpr int KC_BPS = 32;                   // blocks per step (sub values)
constexpr int KC_BLOCKS = NSTEPS * KC_BPS;   // 1024

template<int LL>
DEV void kc_work(int t, int sub,
                 const float* W1, const float* b1, const float* W2, const float* b2,
                 float* ws, unsigned* sBN, float4* tabA, float4* tabB, float* sS) {
  constexpr int FB = LL - 5;        // 16 (g2) / 15 (g3)
  constexpr int HB = FB - 8;        // 8 / 7
  int tx = threadIdx.x;
  int c = ((const int*)ws)[OFF_CT + t];
  int a = c - __popc((unsigned)sub);
  if (a < 0 || a > FB) return;      // block-uniform exit before barriers
  unsigned C = BN.v[FB][a];
  float p = ws[OFF_PCHAIN + t];
  const unsigned* bnf = &BN.v[0][0];
  for (int i = tx; i < 484; i += 256) sBN[i] = bnf[i];
  if (tx < SUMS_STRIDE) sS[tx] = 0.0f;
  // tabA[256]: base (b1 + p*W1col0 + sub-bit terms) + low-8 field bits; tabB[2^HB]: high bits
  for (int i = tx; i < 256 + (1 << HB); i += 256) {
    bool isA = i < 256;
    int e = isA ? i : (i - 256);
    float4 v; float* vp = (float*)&v;
    for (int h = 0; h < 4; h++) {
      float s;
      if (isA) {
        s = b1[h] + p * W1[h * (LL + 1)];
        for (int sbit = 0; sbit < 5; sbit++)
          if ((sub >> sbit) & 1) s += W1[h * (LL + 1) + 1 + FB + sbit];
        for (int j = 0; j < 8; j++)
          if ((e >> j) & 1) s += W1[h * (LL + 1) + 1 + j];
      } else {
        s = 0.0f;
        for (int j = 0; j < HB; j++)
          if ((e >> j) & 1) s += W1[h * (LL + 1) + 1 + 8 + j];
      }
      vp[h] = s;
    }
    if (isA) tabA[e] = v; else tabB[e] = v;
  }
  __syncthreads();
  float w0 = W2[0], w1 = W2[1], w2 = W2[2], w3 = W2[3];
  float b2s = b2[0];
  // balanced rank slice
  unsigned m = C >> 8, rem = C & 255u;
  unsigned l = (unsigned)tx;
  unsigned r0 = l * m + (l < rem ? l : rem);
  int trip = (int)m + (l < rem ? 1 : 0);
  unsigned iv = (trip > 0) ? unrank_lds(sBN, FB, a, r0) : 0u;
  unsigned hi_run = iv >> 8;

  float aE = 0.0f, aW = 0.0f;
  v2f aQa = {0, 0}, aQb = {0, 0}, aWHa = {0, 0}, aWHb = {0, 0};
  v2f rqa = {0, 0}, rqb = {0, 0};
#define G_DECL(k) v2f g##k##a = {0, 0}, g##k##b = {0, 0};
  G_DECL(0) G_DECL(1) G_DECL(2) G_DECL(3) G_DECL(4) G_DECL(5) G_DECL(6) G_DECL(7)
#undef G_DECL

#define FLUSH_HI { unsigned hb = hi_run; \
    while (hb) { int bb_ = __ffs(hb) - 1; hb &= hb - 1u; \
      atomicAdd(&sS[10 + 0 * 21 + 8 + bb_], rqa.x); \
      atomicAdd(&sS[10 + 1 * 21 + 8 + bb_], rqa.y); \
      atomicAdd(&sS[10 + 2 * 21 + 8 + bb_], rqb.x); \
      atomicAdd(&sS[10 + 3 * 21 + 8 + bb_], rqb.y); } }

#pragma unroll 1
  for (int k = 0; k < trip; k++) {
    unsigned hv = iv >> 8;
    if (hv != hi_run) {
      FLUSH_HI;
      hi_run = hv;
      rqa = (v2f){0, 0}; rqb = (v2f){0, 0};
    }
    float4 vA = tabA[iv & 255], vB = tabB[hv];
    float t0 = fast_tanh(vA.x + vB.x);
    float t1 = fast_tanh(vA.y + vB.y);
    float t2 = fast_tanh(vA.z + vB.z);
    float t3 = fast_tanh(vA.w + vB.w);
    float outv = b2s + w0 * t0 + w1 * t1 + w2 * t2 + w3 * t3;
    float e = fast_exp(outv);
    float q0 = outv * (1.0f - t0 * t0) * w0;
    float q1 = outv * (1.0f - t1 * t1) * w1;
    float q2 = outv * (1.0f - t2 * t2) * w2;
    float q3 = outv * (1.0f - t3 * t3) * w3;
    v2f qa = {q0, q1}, qb = {q2, q3};
    aE += e; aW += outv;
    aQa += qa; aQb += qb;
    v2f ov = {outv, outv};
    v2f ta = {t0, t1}, tb = {t2, t3};
    aWHa += ov * ta; aWHb += ov * tb;
    rqa += qa; rqb += qb;
#define G_UPD(k) { float bd = (float)((iv >> k) & 1u); v2f bdv = {bd, bd}; \
    g##k##a += bdv * qa; g##k##b += bdv * qb; }
    G_UPD(0) G_UPD(1) G_UPD(2) G_UPD(3) G_UPD(4) G_UPD(5) G_UPD(6) G_UPD(7)
#undef G_UPD
    iv = gosper(iv);
  }
  if (trip > 0) { FLUSH_HI; }
#undef FLUSH_HI

  // ---- epilogue ----
  int lane = tx & 63;
  float r;
  r = wsum64(aE);    if (lane == 0 && r != 0.0f) atomicAdd(&sS[0], r);
  r = wsum64(aW);    if (lane == 0 && r != 0.0f) atomicAdd(&sS[1], r);
  float S0 = wsum64(aQa.x), S1 = wsum64(aQa.y), S2 = wsum64(aQb.x), S3 = wsum64(aQb.y);
  if (lane == 0) {
    if (S0 != 0.0f) atomicAdd(&sS[2], S0);
    if (S1 != 0.0f) atomicAdd(&sS[3], S1);
    if (S2 != 0.0f) atomicAdd(&sS[4], S2);
    if (S3 != 0.0f) atomicAdd(&sS[5], S3);
  }
  r = wsum64(aWHa.x); if (lane == 0 && r != 0.0f) atomicAdd(&sS[6], r);
  r = wsum64(aWHa.y); if (lane == 0 && r != 0.0f) atomicAdd(&sS[7], r);
  r = wsum64(aWHb.x); if (lane == 0 && r != 0.0f) atomicAdd(&sS[8], r);
  r = wsum64(aWHb.y); if (lane == 0 && r != 0.0f) atomicAdd(&sS[9], r);
#define GF(k) { \
    r = wsum64(g##k##a.x); if (lane == 0 && r != 0.0f) atomicAdd(&sS[10 + 0 * 21 + k], r); \
    r = wsum64(g##k##a.y); if (lane == 0 && r != 0.0f) atomicAdd(&sS[10 + 1 * 21 + k], r); \
    r = wsum64(g##k##b.x); if (lane == 0 && r != 0.0f) atomicAdd(&sS[10 + 2 * 21 + k], r); \
    r = wsum64(g##k##b.y); if (lane == 0 && r != 0.0f) atomicAdd(&sS[10 + 3 * 21 + k], r); }
  GF(0) GF(1) GF(2) GF(3) GF(4) GF(5) GF(6) GF(7)
#undef GF
  // sub bits: combo bit d = FB + sbit
  if (lane == 0) {
    for (int sbit = 0; sbit < 5; sbit++)
      if ((sub >> sbit) & 1) {
        if (S0 != 0.0f) atomicAdd(&sS[10 + 0 * 21 + FB + sbit], S0);
        if (S1 != 0.0f) atomicAdd(&sS[10 + 1 * 21 + FB + sbit], S1);
        if (S2 != 0.0f) atomicAdd(&sS[10 + 2 * 21 + FB + sbit], S2);
        if (S3 != 0.0f) atomicAdd(&sS[10 + 3 * 21 + FB + sbit], S3);
      }
  }
  __syncthreads();
  if (tx < SUMS_STRIDE) {
    float v = sS[tx];
    if (v != 0.0f) gatomic(&ws[OFF_SUMS + t * SUMS_STRIDE + tx], v);
  }
}

__global__ __launch_bounds__(256) void kc(
    const float* W1_2, const float* b1_2, const float* W2_2, const float* b2_2,
    const float* W1_3, const float* b1_3, const float* W2_3, const float* b2_3,
    float* ws) {
  __shared__ unsigned sBN[484];
  __shared__ float4 tabA[256], tabB[256];
  __shared__ float sS[SUMS_STRIDE];
  int b = blockIdx.x;
  int t = b >> 5, sub = b & 31;
  if (t < NSTEP2) kc_work<21>(t, sub, W1_2, b1_2, W2_2, b2_2, ws, sBN, tabA, tabB, sS);
  else            kc_work<20>(t, sub, W1_3, b1_3, W2_3, b2_3, ws, sBN, tabA, tabB, sS);
}

// =================== Kernel D: finalize gradient outputs ===================
__global__ __launch_bounds__(256) void kd(
                   const float* W1_2, const float* b1_2, const float* W2_2, const float* b2_2,
                   const float* W1_3, const float* b1_3, const float* W2_3, const float* b2_3,
                   const float* ws, float* out) {
  __shared__ float sS[NSTEPS * SUMS_STRIDE];   // 12 KB
  __shared__ float sk_s[NSTEPS][4], hk_s[NSTEPS][4], pp_s[NSTEPS], s0i_s[NSTEPS];
  int tx = threadIdx.x;
  for (int i = tx; i < NSTEPS * SUMS_STRIDE; i += 256) sS[i] = ws[OFF_SUMS + i];
  __syncthreads();
  if (tx < NSTEPS) {
    int t = tx; int g = (t < NSTEP2) ? 0 : 1; int L = g ? L3 : L2;
    const float* W1 = g ? W1_3 : W1_2;
    const float* W2 = g ? W2_3 : W2_2;
    float p = ws[OFF_PCHAIN + t];
    pp_s[t] = p;
    s0i_s[t] = 1.0f / sS[t * SUMS_STRIDE + 0];
    for (int h = 0; h < 4; h++) {
      float hk = fast_tanh(ws[OFF_KEYB + t * 4 + h] + p * W1[h * (L + 1)]);
      hk_s[t][h] = hk;
      sk_s[t][h] = (1.0f - hk * hk) * W2[h];
    }
  }
  __syncthreads();
  const unsigned* cbp = (const unsigned*)ws;
  for (int o = 33 + tx; o < 223; o += blockDim.x) {
    float val = 0.0f;
    if (o < 130) {                           // ---- group2 grads ----
      if (o < 121) {                         // W1_2 grad [4][22]
        int e = o - 33; int h = e / 22, d = e % 22;
        for (int t = 0; t < NSTEP2; t++) {
          float xk = (d == 0) ? pp_s[t] : (float)((cbp[OFF_CB + t] >> (d - 1)) & 1);
          float gs = (d == 0) ? pp_s[t] * sS[t * SUMS_STRIDE + 2 + h]
                              : sS[t * SUMS_STRIDE + 10 + h * 21 + (d - 1)];
          val += sk_s[t][h] * xk - gs * s0i_s[t];
        }
      } else if (o < 125) { int h = o - 121;
        for (int t = 0; t < NSTEP2; t++) val += sk_s[t][h] - sS[t * SUMS_STRIDE + 2 + h] * s0i_s[t];
      } else if (o < 129) { int h = o - 125;
        for (int t = 0; t < NSTEP2; t++) val += hk_s[t][h] - sS[t * SUMS_STRIDE + 6 + h] * s0i_s[t];
      } else {
        for (int t = 0; t < NSTEP2; t++) val += 1.0f - sS[t * SUMS_STRIDE + 1] * s0i_s[t];
      }
    } else {                                 // ---- group3 grads ----
      if (o < 214) {                         // W1_3 grad [4][21]
        int e = o - 130; int h = e / 21, d = e % 21;
        for (int t = NSTEP2; t < NSTEPS; t++) {
          float xk = (d == 0) ? pp_s[t] : (float)((cbp[OFF_CB + t] >> (d - 1)) & 1);
          float gs = (d == 0) ? pp_s[t] * sS[t * SUMS_STRIDE + 2 + h]
                              : sS[t * SUMS_STRIDE + 10 + h * 21 + (d - 1)];
          val += sk_s[t][h] * xk - gs * s0i_s[t];
        }
      } else if (o < 218) { int h = o - 214;
        for (int t = NSTEP2; t < NSTEPS; t++) val += sk_s[t][h] - sS[t * SUMS_STRIDE + 2 + h] * s0i_s[t];
      } else if (o < 222) { int h = o - 218;
        for (int t = NSTEP2; t < NSTEPS; t++) val += hk_s[t][h] - sS[t * SUMS_STRIDE + 6 + h] * s0i_s[t];
      } else {
        for (int t = NSTEP2; t < NSTEPS; t++) val += 1.0f - sS[t * SUMS_STRIDE + 1] * s0i_s[t];
      }
    }
    out[o] = val;
  }
}

extern "C" void kernel_launch(void* const* d_in, const int* in_sizes, int n_in,
                              void* d_out, int out_size, void* d_ws, size_t ws_size,
                              hipStream_t stream) {
  const float* p0   = (const float*)d_in[0];
  const float* sel  = (const float*)d_in[1];
  const float* W1_2 = (const float*)d_in[2]; const float* b1_2 = (const float*)d_in[3];
  const float* W2_2 = (const float*)d_in[4]; const float* b2_2 = (const float*)d_in[5];
  const float* W1_3 = (const float*)d_in[6]; const float* b1_3 = (const float*)d_in[7];
  const float* W2_3 = (const float*)d_in[8]; const float* b2_3 = (const float*)d_in[9];
  float* out = (float*)d_out;
  float* ws  = (float*)d_ws;
  hipLaunchKernelGGL(kz, dim3(1), dim3(256), 0, stream, p0, sel, W1_2, b1_2, W1_3, b1_3, ws);
  hipLaunchKernelGGL(ka, dim3(KAOFF.total), dim3(256), 0, stream,
                     W1_2, b1_2, W2_2, b2_2, W1_3, b1_3, W2_3, b2_3, ws);
  hipLaunchKernelGGL(kb, dim3(1), dim3(64), 0, stream, p0,
                     W1_2, b1_2, W2_2, b2_2, W1_3, b1_3, W2_3, b2_3, ws, out);
  hipLaunchKernelGGL(kc, dim3(KC_BLOCKS), dim3(256), 0, stream,
                     W1_2, b1_2, W2_2, b2_2, W1_3, b1_3, W2_3, b2_3, ws);
  hipLaunchKernelGGL(kd, dim3(1), dim3(256), 0, stream,
                     W1_2, b1_2, W2_2, b2_2, W1_3, b1_3, W2_3, b2_3, ws, out);
}

// Round 11
// 109.203 us; speedup vs baseline: 1.2333x; 1.2333x over previous
//
#include <hip/hip_runtime.h>
#include <cstdint>
#include <cmath>

#define DEV __device__ __forceinline__

constexpr int SEL = 20;
constexpr int NSTEP2 = 10, NSTEP3 = 22, NSTEPS = 32;
constexpr int L2 = SEL + 1;   // 21 bits, group2
constexpr int L3 = SEL;       // 20 bits, group3
constexpr int P = 2;          // Chebyshev nodes (linear interp; lnT curvature ~0.09 -> ~0.5% err)
constexpr int FBE = 7;        // enumerated low bits
constexpr int FBS2 = L2 - FBE;   // 14
constexpr int FBS3 = L3 - FBE;   // 13
constexpr int NPAT2 = 1 << FBS2; // 16384
constexpr int NPAT3 = 1 << FBS3; // 8192

typedef float v2f __attribute__((ext_vector_type(2)));

// ---- ws layout (float indices) ----
constexpr int OFF_T      = 0;                               // T[2][22][P] = 88
constexpr int OFF_SUMS   = OFF_T + 2 * 22 * P;
constexpr int SUMS_STRIDE = 96;
constexpr int OFF_PCHAIN = OFF_SUMS + NSTEPS * SUMS_STRIDE;
constexpr int OFF_KEYB   = OFF_PCHAIN + 40;
constexpr int OFF_CT     = OFF_KEYB + 128;
constexpr int OFF_CB     = OFF_CT + 32;
constexpr int OFF_NEED   = OFF_CB + 32;
constexpr int OFF_ZEND   = OFF_NEED + 8;                    // zero range end
constexpr int OFF_PAT2   = OFF_ZEND;                        // uint[16384]
constexpr int OFF_PAT3   = OFF_PAT2 + NPAT2;                // uint[8192]

constexpr float K2E = 2.8853900817779268f;   // 2*log2(e)
constexpr float KE  = 1.4426950408889634f;   // log2(e)

constexpr float CP0 = 0.85355339059f, CP1 = 0.14644660941f; // 2-node Chebyshev on (0,1)

struct Binom { unsigned v[22][22]; };
constexpr Binom make_binom() {
  Binom b{};
  for (int n = 0; n < 22; n++) {
    b.v[n][0] = 1;
    for (int k = 1; k < 22; k++)
      b.v[n][k] = (k > n) ? 0u : (k == n ? 1u : b.v[n - 1][k - 1] + b.v[n - 1][k]);
  }
  return b;
}
__device__ constexpr Binom BN = make_binom();

DEV float fast_tanh(float x) {
  float e = exp2f(x * K2E);
  return 1.0f - 2.0f * __builtin_amdgcn_rcpf(e + 1.0f);
}
DEV float fast_exp(float x) { return exp2f(x * KE); }
DEV void gatomic(float* p, float v) { unsafeAtomicAdd(p, v); }

DEV unsigned gosper(unsigned cmb) {
  unsigned u = cmb & (~cmb + 1u);
  unsigned v = cmb + u;
  return v | ((cmb ^ v) >> (1 + __ffs(u)));
}

DEV float wsum64(float v) {
  for (int m = 1; m < 64; m <<= 1) v += __shfl_xor(v, m);
  return v;
}

// =================== Kernel Z: init + popc-sorted pattern tables ===================
__global__ void kz(const float* p0, const float* sel,
                   const float* W1_2, const float* b1_2,
                   const float* W1_3, const float* b1_3, float* ws) {
  int tx = threadIdx.x;
  if (blockIdx.x == 0) {
    for (int i = tx; i < OFF_ZEND; i += blockDim.x) ws[i] = 0.0f;
    __syncthreads();
    if (tx < NSTEPS) {
      int t = tx;
      int g = (t < NSTEP2) ? 0 : 1;
      int L = g ? L3 : L2;
      const float* sbase = sel + (g ? (NSTEP2 * L2 + (t - NSTEP2) * L3) : t * L2);
      unsigned cb = 0; int c = 0;
      for (int d = 0; d < L; d++)
        if (sbase[d] > 0.5f) { cb |= 1u << d; c++; }
      ((int*)ws)[OFF_CT + t] = c;
      ((unsigned*)ws)[OFF_CB + t] = cb;
      atomicOr(&((unsigned*)ws)[OFF_NEED + g], 1u << c);
      const float* W1 = g ? W1_3 : W1_2;
      const float* b1 = g ? b1_3 : b1_2;
      for (int h = 0; h < 4; h++) {
        float s = b1[h];
        for (int d = 0; d < L; d++)
          if ((cb >> d) & 1) s += W1[h * (L + 1) + 1 + d];
        ws[OFF_KEYB + t * 4 + h] = s;
      }
      if (tx == 0) ws[OFF_PCHAIN] = p0[0];
    }
  } else {
    int r = (blockIdx.x - 1) * 256 + tx;   // 0..24575
    int NB, rr, off;
    if (r < NPAT2) { NB = FBS2; rr = r; off = OFF_PAT2; }
    else           { NB = FBS3; rr = r - NPAT2; off = OFF_PAT3; }
    int k = 0; unsigned base = 0;
    for (int kk = 0; kk <= NB; kk++) {
      unsigned sz = BN.v[NB][kk];
      if ((unsigned)rr < base + sz) { k = kk; break; }
      base += sz;
    }
    unsigned local = (unsigned)rr - base;
    unsigned pat = 0; int kk = k;
    for (int bb = NB - 1; bb >= 0 && kk > 0; bb--) {
      unsigned cnt = BN.v[bb][kk];
      if (local >= cnt) { pat |= 1u << bb; local -= cnt; kk--; }
    }
    ((unsigned*)ws)[off + rr] = pat;
  }
}

// =================== shared tab builder ===================
// tabEX[128]: exp2(K2E * sum_{j<7,bit} W1[h][1+j])    (exp-form, low enumerated bits)
// tabS0[128]: add_h + sum_{j<7,bit} W1[h][1+7+j]      (structural bits 0..6)
// tabS1[1<<(LL-14)]: sum_{bit} W1[h][1+14+j]          (structural bits 7..)
template<int LL>
DEV void build_tabs(const float* W1, float4 add,
                    float4* tabEX, float4* tabS0, float4* tabS1) {
  constexpr int NS1 = 1 << (LL - 14);
  int tx = threadIdx.x;
  for (int i = tx; i < 256 + NS1; i += 256) {
    if (i < 128) {
      int e = i;
      float s0 = 0, s1 = 0, s2 = 0, s3 = 0;
      for (int j = 0; j < 7; j++) if ((e >> j) & 1) {
        s0 += W1[0 * (LL + 1) + 1 + j]; s1 += W1[1 * (LL + 1) + 1 + j];
        s2 += W1[2 * (LL + 1) + 1 + j]; s3 += W1[3 * (LL + 1) + 1 + j];
      }
      tabEX[e] = make_float4(exp2f(K2E * s0), exp2f(K2E * s1), exp2f(K2E * s2), exp2f(K2E * s3));
    } else if (i < 256) {
      int e = i - 128;
      float s0 = add.x, s1 = add.y, s2 = add.z, s3 = add.w;
      for (int j = 0; j < 7; j++) if ((e >> j) & 1) {
        s0 += W1[0 * (LL + 1) + 1 + 7 + j]; s1 += W1[1 * (LL + 1) + 1 + 7 + j];
        s2 += W1[2 * (LL + 1) + 1 + 7 + j]; s3 += W1[3 * (LL + 1) + 1 + 7 + j];
      }
      tabS0[e] = make_float4(s0, s1, s2, s3);
    } else {
      int e = i - 256;
      float s0 = 0, s1 = 0, s2 = 0, s3 = 0;
      for (int j = 0; j < LL - 14; j++) if ((e >> j) & 1) {
        s0 += W1[0 * (LL + 1) + 1 + 14 + j]; s1 += W1[1 * (LL + 1) + 1 + 14 + j];
        s2 += W1[2 * (LL + 1) + 1 + 14 + j]; s3 += W1[3 * (LL + 1) + 1 + 14 + j];
      }
      tabS1[e] = make_float4(s0, s1, s2, s3);
    }
  }
}

// =================== Kernel A: per-class tabulation of T[g][c][j] ===================
constexpr int KA_B2 = NPAT2 / 256;  // 64
constexpr int KA_B3 = NPAT3 / 256;  // 32
constexpr int KA_BLOCKS = 22 * KA_B2 + 21 * KA_B3;  // 2080

template<int LL>
DEV void ka_work(int g, int c, int sub,
                 const float* W1, const float* b1, const float* W2, const float* b2,
                 float* ws, float4* tabEX, float4* tabS0, float4* tabS1, float* sT) {
  int tx = threadIdx.x;
  float4 add = make_float4(b1[0], b1[1], b1[2], b1[3]);
  build_tabs<LL>(W1, add, tabEX, tabS0, tabS1);
  if (tx < P) sT[tx] = 0.0f;
  __syncthreads();
  int r = sub * 256 + tx;
  unsigned pat = ((const unsigned*)ws)[(LL == 21 ? OFF_PAT2 : OFF_PAT3) + r];
  int ce = c - __popc(pat);
  int trip = (ce >= 0 && ce <= FBE) ? (int)BN.v[FBE][ce] : 0;
  float4 vS0 = tabS0[pat & 127];
  float4 vS1 = tabS1[pat >> 7];
  float E0 = exp2f(K2E * (vS0.x + vS1.x));
  float E1 = exp2f(K2E * (vS0.y + vS1.y));
  float E2 = exp2f(K2E * (vS0.z + vS1.z));
  float E3 = exp2f(K2E * (vS0.w + vS1.w));
  float a0 = W1[0], a1 = W1[LL + 1], a2 = W1[2 * (LL + 1)], a3 = W1[3 * (LL + 1)];
  float w0 = W2[0], w1 = W2[1], w2 = W2[2], w3 = W2[3];
  float W0 = b2[0] + w0 + w1 + w2 + w3;
  float m0 = -2.0f * w0, m1 = -2.0f * w1, m2 = -2.0f * w2, m3 = -2.0f * w3;
  // EA[j][h] = E_h * exp2(K2E * p_j * a_h)
  float EA00 = E0 * exp2f(K2E * CP0 * a0), EA01 = E1 * exp2f(K2E * CP0 * a1);
  float EA02 = E2 * exp2f(K2E * CP0 * a2), EA03 = E3 * exp2f(K2E * CP0 * a3);
  float EA10 = E0 * exp2f(K2E * CP1 * a0), EA11 = E1 * exp2f(K2E * CP1 * a1);
  float EA12 = E2 * exp2f(K2E * CP1 * a2), EA13 = E3 * exp2f(K2E * CP1 * a3);
  float acc0 = 0.0f, acc1 = 0.0f;
  unsigned iv = (trip > 0) ? ((1u << ce) - 1u) : 0u;
#pragma unroll 1
  for (int k = 0; k < trip; k++) {
    float4 tE = tabEX[iv];
    float o0 = W0, o1 = W0, rr;
    rr = __builtin_amdgcn_rcpf(fmaf(tE.x, EA00, 1.0f)); o0 = fmaf(m0, rr, o0);
    rr = __builtin_amdgcn_rcpf(fmaf(tE.y, EA01, 1.0f)); o0 = fmaf(m1, rr, o0);
    rr = __builtin_amdgcn_rcpf(fmaf(tE.z, EA02, 1.0f)); o0 = fmaf(m2, rr, o0);
    rr = __builtin_amdgcn_rcpf(fmaf(tE.w, EA03, 1.0f)); o0 = fmaf(m3, rr, o0);
    rr = __builtin_amdgcn_rcpf(fmaf(tE.x, EA10, 1.0f)); o1 = fmaf(m0, rr, o1);
    rr = __builtin_amdgcn_rcpf(fmaf(tE.y, EA11, 1.0f)); o1 = fmaf(m1, rr, o1);
    rr = __builtin_amdgcn_rcpf(fmaf(tE.z, EA12, 1.0f)); o1 = fmaf(m2, rr, o1);
    rr = __builtin_amdgcn_rcpf(fmaf(tE.w, EA13, 1.0f)); o1 = fmaf(m3, rr, o1);
    acc0 += exp2f(KE * o0);
    acc1 += exp2f(KE * o1);
    iv = gosper(iv);
  }
  float v0 = wsum64(acc0), v1 = wsum64(acc1);
  if ((tx & 63) == 0) {
    if (v0 != 0.0f) atomicAdd(&sT[0], v0);
    if (v1 != 0.0f) atomicAdd(&sT[1], v1);
  }
  __syncthreads();
  if (tx < P) {
    float v = sT[tx];
    if (v != 0.0f) gatomic(&ws[OFF_T + (g * 22 + c) * P + tx], v);
  }
}

__global__ __launch_bounds__(256) void ka(
    const float* W1_2, const float* b1_2, const float* W2_2, const float* b2_2,
    const float* W1_3, const float* b1_3, const float* W2_3, const float* b2_3,
    float* ws) {
  __shared__ float4 tabEX[128], tabS0[128], tabS1[128];
  __shared__ float sT[P];
  int b = blockIdx.x;
  int g, c, sub;
  if (b < 22 * KA_B2) { g = 0; c = b / KA_B2; sub = b % KA_B2; }
  else { int b3 = b - 22 * KA_B2; g = 1; c = b3 / KA_B3; sub = b3 % KA_B3; }
  unsigned need = ((const unsigned*)ws)[OFF_NEED + g];
  if (!((need >> c) & 1)) return;
  if (g == 0) ka_work<21>(0, c, sub, W1_2, b1_2, W2_2, b2_2, ws, tabEX, tabS0, tabS1, sT);
  else        ka_work<20>(1, c, sub, W1_3, b1_3, W2_3, b2_3, ws, tabEX, tabS0, tabS1, sT);
}

// =================== Kernel B: prob chain, 64-lane cooperative ===================
__global__ __launch_bounds__(64) void kb(const float* p0in,
                   const float* W1_2, const float* b1_2, const float* W2_2, const float* b2_2,
                   const float* W1_3, const float* b1_3, const float* W2_3, const float* b2_3,
                   float* ws, float* out) {
  __shared__ float sT[2 * 22 * P];
  __shared__ float sKEYB[128], sW1c0[8], sW2[8], sB2[2];
  __shared__ int sCT[32];
  int lane = threadIdx.x;
  for (int i = lane; i < 2 * 22 * P; i += 64) sT[i] = ws[OFF_T + i];
  for (int i = lane; i < 128; i += 64) sKEYB[i] = ws[OFF_KEYB + i];
  if (lane < 32) sCT[lane] = ((const int*)ws)[OFF_CT + lane];
  if (lane < 4) {
    sW1c0[lane]     = W1_2[lane * (L2 + 1)];
    sW1c0[4 + lane] = W1_3[lane * (L3 + 1)];
    sW2[lane]     = W2_2[lane];
    sW2[4 + lane] = W2_3[lane];
  }
  if (lane == 0) { sB2[0] = b2_2[0]; sB2[1] = b2_3[0]; }
  __syncthreads();
  float p = p0in[0];
  if (lane == 0) out[0] = p;
  int h = lane & 3;
#pragma unroll 1
  for (int tt = 0; tt < NSTEPS; tt++) {
    int g = (tt < NSTEP2) ? 0 : 1;
    int c = sCT[tt];
    float hk = fast_tanh(sKEYB[tt * 4 + h] + p * sW1c0[g * 4 + h]);
    float contrib = sW2[g * 4 + h] * hk;
    contrib += __shfl_xor(contrib, 1);
    contrib += __shfl_xor(contrib, 2);
    float outk = sB2[g] + contrib;
    float T0 = sT[(g * 22 + c) * P + 0], T1 = sT[(g * 22 + c) * P + 1];
    float d0 = p - CP0; if (fabsf(d0) < 1e-9f) d0 = (d0 < 0.0f) ? -1e-9f : 1e-9f;
    float d1 = p - CP1; if (fabsf(d1) < 1e-9f) d1 = (d1 < 0.0f) ? -1e-9f : 1e-9f;
    float q0 = 1.0f / d0, q1 = -1.0f / d1;
    float Se = (q0 * T0 + q1 * T1) / (q0 + q1);
    p = fast_exp(outk) / Se;
    if (lane == 0) { out[1 + tt] = p; ws[OFF_PCHAIN + 1 + tt] = p; }
  }
}

// =================== Kernel C: popc-sorted structural enumeration ===================
constexpr int KC_B2 = NPAT2 / 256;   // 64 blocks/step (g2)
constexpr int KC_B3 = NPAT3 / 256;   // 32 blocks/step (g3)
constexpr int KC_BLOCKS = NSTEP2 * KC_B2 + NSTEP3 * KC_B3;  // 1344

template<int LL>
DEV void kc_work(int t, int sub,
                 const float* W1, const float* b1, const float* W2, const float* b2,
                 float* ws, float4* tabEX, float4* tabS0, float4* tabS1, float* sS) {
  constexpr int FS = LL - FBE;   // structural bit count: 14 / 13
  int tx = threadIdx.x;
  int c = ((const int*)ws)[OFF_CT + t];
  float p = ws[OFF_PCHAIN + t];
  float4 add = make_float4(b1[0] + p * W1[0 * (LL + 1)], b1[1] + p * W1[1 * (LL + 1)],
                           b1[2] + p * W1[2 * (LL + 1)], b1[3] + p * W1[3 * (LL + 1)]);
  build_tabs<LL>(W1, add, tabEX, tabS0, tabS1);
  if (tx < SUMS_STRIDE) sS[tx] = 0.0f;
  __syncthreads();
  int r = sub * 256 + tx;
  unsigned pat = ((const unsigned*)ws)[(LL == 21 ? OFF_PAT2 : OFF_PAT3) + r];
  int ce = c - __popc(pat);
  int trip = (ce >= 0 && ce <= FBE) ? (int)BN.v[FBE][ce] : 0;
  float4 vS0 = tabS0[pat & 127];
  float4 vS1 = tabS1[pat >> 7];
  float EbS0 = exp2f(K2E * (vS0.x + vS1.x));
  float EbS1 = exp2f(K2E * (vS0.y + vS1.y));
  float EbS2 = exp2f(K2E * (vS0.z + vS1.z));
  float EbS3 = exp2f(K2E * (vS0.w + vS1.w));
  float w0 = W2[0], w1 = W2[1], w2 = W2[2], w3 = W2[3];
  float b2s = b2[0];

  float aE = 0.0f, aW = 0.0f;
  v2f aQa = {0, 0}, aQb = {0, 0}, aWHa = {0, 0}, aWHb = {0, 0};
#define G_DECL(k) v2f g##k##a = {0, 0}, g##k##b = {0, 0};
  G_DECL(0) G_DECL(1) G_DECL(2) G_DECL(3) G_DECL(4) G_DECL(5) G_DECL(6)
#undef G_DECL

  unsigned iv = (trip > 0) ? ((1u << ce) - 1u) : 0u;
#pragma unroll 1
  for (int k = 0; k < trip; k++) {
    float4 tE = tabEX[iv];   // iv wave-uniform -> broadcast read
    float r0 = __builtin_amdgcn_rcpf(fmaf(tE.x, EbS0, 1.0f));
    float r1 = __builtin_amdgcn_rcpf(fmaf(tE.y, EbS1, 1.0f));
    float r2 = __builtin_amdgcn_rcpf(fmaf(tE.z, EbS2, 1.0f));
    float r3 = __builtin_amdgcn_rcpf(fmaf(tE.w, EbS3, 1.0f));
    float t0 = fmaf(-2.0f, r0, 1.0f);
    float t1 = fmaf(-2.0f, r1, 1.0f);
    float t2 = fmaf(-2.0f, r2, 1.0f);
    float t3 = fmaf(-2.0f, r3, 1.0f);
    float outv = b2s + w0 * t0 + w1 * t1 + w2 * t2 + w3 * t3;
    float e = fast_exp(outv);
    float q0 = outv * (1.0f - t0 * t0) * w0;
    float q1 = outv * (1.0f - t1 * t1) * w1;
    float q2 = outv * (1.0f - t2 * t2) * w2;
    float q3 = outv * (1.0f - t3 * t3) * w3;
    v2f qa = {q0, q1}, qb = {q2, q3};
    aE += e; aW += outv;
    aQa += qa; aQb += qb;
    v2f ov = {outv, outv};
    v2f ta = {t0, t1}, tb = {t2, t3};
    aWHa += ov * ta; aWHb += ov * tb;
#define G_UPD(k) { float bd = (float)((iv >> k) & 1u); v2f bdv = {bd, bd}; \
    g##k##a += bdv * qa; g##k##b += bdv * qb; }
    G_UPD(0) G_UPD(1) G_UPD(2) G_UPD(3) G_UPD(4) G_UPD(5) G_UPD(6)
#undef G_UPD
    iv = gosper(iv);
  }

  // ---- epilogue ----
  int lane = tx & 63;
  float rr;
  rr = wsum64(aE); if (lane == 0 && rr != 0.0f) atomicAdd(&sS[0], rr);
  rr = wsum64(aW); if (lane == 0 && rr != 0.0f) atomicAdd(&sS[1], rr);
  rr = wsum64(aQa.x); if (lane == 0 && rr != 0.0f) atomicAdd(&sS[2], rr);
  rr = wsum64(aQa.y); if (lane == 0 && rr != 0.0f) atomicAdd(&sS[3], rr);
  rr = wsum64(aQb.x); if (lane == 0 && rr != 0.0f) atomicAdd(&sS[4], rr);
  rr = wsum64(aQb.y); if (lane == 0 && rr != 0.0f) atomicAdd(&sS[5], rr);
  rr = wsum64(aWHa.x); if (lane == 0 && rr != 0.0f) atomicAdd(&sS[6], rr);
  rr = wsum64(aWHa.y); if (lane == 0 && rr != 0.0f) atomicAdd(&sS[7], rr);
  rr = wsum64(aWHb.x); if (lane == 0 && rr != 0.0f) atomicAdd(&sS[8], rr);
  rr = wsum64(aWHb.y); if (lane == 0 && rr != 0.0f) atomicAdd(&sS[9], rr);
  // enumerated bits d = 0..6
#define GF(k) { \
    rr = wsum64(g##k##a.x); if (lane == 0 && rr != 0.0f) atomicAdd(&sS[10 + 0 * 21 + k], rr); \
    rr = wsum64(g##k##a.y); if (lane == 0 && rr != 0.0f) atomicAdd(&sS[10 + 1 * 21 + k], rr); \
    rr = wsum64(g##k##b.x); if (lane == 0 && rr != 0.0f) atomicAdd(&sS[10 + 2 * 21 + k], rr); \
    rr = wsum64(g##k##b.y); if (lane == 0 && rr != 0.0f) atomicAdd(&sS[10 + 3 * 21 + k], rr); }
  GF(0) GF(1) GF(2) GF(3) GF(4) GF(5) GF(6)
#undef GF
  // structural bits d = FBE + j, via per-lane mask of the pattern
#pragma unroll
  for (int j = 0; j < 14; j++) {
    if (j < FS) {
      float m = (float)((pat >> j) & 1u);
      rr = wsum64(m * aQa.x); if (lane == 0 && rr != 0.0f) atomicAdd(&sS[10 + 0 * 21 + FBE + j], rr);
      rr = wsum64(m * aQa.y); if (lane == 0 && rr != 0.0f) atomicAdd(&sS[10 + 1 * 21 + FBE + j], rr);
      rr = wsum64(m * aQb.x); if (lane == 0 && rr != 0.0f) atomicAdd(&sS[10 + 2 * 21 + FBE + j], rr);
      rr = wsum64(m * aQb.y); if (lane == 0 && rr != 0.0f) atomicAdd(&sS[10 + 3 * 21 + FBE + j], rr);
    }
  }
  __syncthreads();
  if (tx < SUMS_STRIDE) {
    float v = sS[tx];
    if (v != 0.0f) gatomic(&ws[OFF_SUMS + t * SUMS_STRIDE + tx], v);
  }
}

__global__ __launch_bounds__(256) void kc(
    const float* W1_2, const float* b1_2, const float* W2_2, const float* b2_2,
    const float* W1_3, const float* b1_3, const float* W2_3, const float* b2_3,
    float* ws) {
  __shared__ float4 tabEX[128], tabS0[128], tabS1[128];
  __shared__ float sS[SUMS_STRIDE];
  int b = blockIdx.x;
  if (b < NSTEP2 * KC_B2) {
    int t = b / KC_B2, sub = b % KC_B2;
    kc_work<21>(t, sub, W1_2, b1_2, W2_2, b2_2, ws, tabEX, tabS0, tabS1, sS);
  } else {
    int b3 = b - NSTEP2 * KC_B2;
    int t = NSTEP2 + b3 / KC_B3, sub = b3 % KC_B3;
    kc_work<20>(t, sub, W1_3, b1_3, W2_3, b2_3, ws, tabEX, tabS0, tabS1, sS);
  }
}

// =================== Kernel D: finalize gradient outputs ===================
__global__ __launch_bounds__(256) void kd(
                   const float* W1_2, const float* b1_2, const float* W2_2, const float* b2_2,
                   const float* W1_3, const float* b1_3, const float* W2_3, const float* b2_3,
                   const float* ws, float* out) {
  __shared__ float sS[NSTEPS * SUMS_STRIDE];
  __shared__ float sk_s[NSTEPS][4], hk_s[NSTEPS][4], pp_s[NSTEPS], s0i_s[NSTEPS];
  int tx = threadIdx.x;
  for (int i = tx; i < NSTEPS * SUMS_STRIDE; i += 256) sS[i] = ws[OFF_SUMS + i];
  __syncthreads();
  if (tx < NSTEPS) {
    int t = tx; int g = (t < NSTEP2) ? 0 : 1; int L = g ? L3 : L2;
    const float* W1 = g ? W1_3 : W1_2;
    const float* W2 = g ? W2_3 : W2_2;
    float p = ws[OFF_PCHAIN + t];
    pp_s[t] = p;
    s0i_s[t] = 1.0f / sS[t * SUMS_STRIDE + 0];
    for (int h = 0; h < 4; h++) {
      float hk = fast_tanh(ws[OFF_KEYB + t * 4 + h] + p * W1[h * (L + 1)]);
      hk_s[t][h] = hk;
      sk_s[t][h] = (1.0f - hk * hk) * W2[h];
    }
  }
  __syncthreads();
  const unsigned* cbp = (const unsigned*)ws;
  for (int o = 33 + tx; o < 223; o += blockDim.x) {
    float val = 0.0f;
    if (o < 130) {
      if (o < 121) {
        int e = o - 33; int h = e / 22, d = e % 22;
        for (int t = 0; t < NSTEP2; t++) {
          float xk = (d == 0) ? pp_s[t] : (float)((cbp[OFF_CB + t] >> (d - 1)) & 1);
          float gs = (d == 0) ? pp_s[t] * sS[t * SUMS_STRIDE + 2 + h]
                              : sS[t * SUMS_STRIDE + 10 + h * 21 + (d - 1)];
          val += sk_s[t][h] * xk - gs * s0i_s[t];
        }
      } else if (o < 125) { int h = o - 121;
        for (int t = 0; t < NSTEP2; t++) val += sk_s[t][h] - sS[t * SUMS_STRIDE + 2 + h] * s0i_s[t];
      } else if (o < 129) { int h = o - 125;
        for (int t = 0; t < NSTEP2; t++) val += hk_s[t][h] - sS[t * SUMS_STRIDE + 6 + h] * s0i_s[t];
      } else {
        for (int t = 0; t < NSTEP2; t++) val += 1.0f - sS[t * SUMS_STRIDE + 1] * s0i_s[t];
      }
    } else {
      if (o < 214) {
        int e = o - 130; int h = e / 21, d = e % 21;
        for (int t = NSTEP2; t < NSTEPS; t++) {
          float xk = (d == 0) ? pp_s[t] : (float)((cbp[OFF_CB + t] >> (d - 1)) & 1);
          float gs = (d == 0) ? pp_s[t] * sS[t * SUMS_STRIDE + 2 + h]
                              : sS[t * SUMS_STRIDE + 10 + h * 21 + (d - 1)];
          val += sk_s[t][h] * xk - gs * s0i_s[t];
        }
      } else if (o < 218) { int h = o - 214;
        for (int t = NSTEP2; t < NSTEPS; t++) val += sk_s[t][h] - sS[t * SUMS_STRIDE + 2 + h] * s0i_s[t];
      } else if (o < 222) { int h = o - 218;
        for (int t = NSTEP2; t < NSTEPS; t++) val += hk_s[t][h] - sS[t * SUMS_STRIDE + 6 + h] * s0i_s[t];
      } else {
        for (int t = NSTEP2; t < NSTEPS; t++) val += 1.0f - sS[t * SUMS_STRIDE + 1] * s0i_s[t];
      }
    }
    out[o] = val;
  }
}

extern "C" void kernel_launch(void* const* d_in, const int* in_sizes, int n_in,
                              void* d_out, int out_size, void* d_ws, size_t ws_size,
                              hipStream_t stream) {
  const float* p0   = (const float*)d_in[0];
  const float* sel  = (const float*)d_in[1];
  const float* W1_2 = (const float*)d_in[2]; const float* b1_2 = (const float*)d_in[3];
  const float* W2_2 = (const float*)d_in[4]; const float* b2_2 = (const float*)d_in[5];
  const float* W1_3 = (const float*)d_in[6]; const float* b1_3 = (const float*)d_in[7];
  const float* W2_3 = (const float*)d_in[8]; const float* b2_3 = (const float*)d_in[9];
  float* out = (float*)d_out;
  float* ws  = (float*)d_ws;
  hipLaunchKernelGGL(kz, dim3(1 + (NPAT2 + NPAT3) / 256), dim3(256), 0, stream,
                     p0, sel, W1_2, b1_2, W1_3, b1_3, ws);
  hipLaunchKernelGGL(ka, dim3(KA_BLOCKS), dim3(256), 0, stream,
                     W1_2, b1_2, W2_2, b2_2, W1_3, b1_3, W2_3, b2_3, ws);
  hipLaunchKernelGGL(kb, dim3(1), dim3(64), 0, stream, p0,
                     W1_2, b1_2, W2_2, b2_2, W1_3, b1_3, W2_3, b2_3, ws, out);
  hipLaunchKernelGGL(kc, dim3(KC_BLOCKS), dim3(256), 0, stream,
                     W1_2, b1_2, W2_2, b2_2, W1_3, b1_3, W2_3, b2_3, ws);
  hipLaunchKernelGGL(kd, dim3(1), dim3(256), 0, stream,
                     W1_2, b1_2, W2_2, b2_2, W1_3, b1_3, W2_3, b2_3, ws, out);
}

// Round 12
// 96.372 us; speedup vs baseline: 1.3975x; 1.1331x over previous
//
#include <hip/hip_runtime.h>
#include <cstdint>
#include <cmath>

#define DEV __device__ __forceinline__

constexpr int SEL = 20;
constexpr int NSTEP2 = 10, NSTEP3 = 22, NSTEPS = 32;
constexpr int L2 = SEL + 1;   // 21 bits, group2
constexpr int L3 = SEL;       // 20 bits, group3
constexpr int P = 2;          // Chebyshev nodes (linear interp; lnT curvature ~0.09 -> ~0.5% err)
constexpr int FBE = 7;        // enumerated low bits
constexpr int FBS2 = L2 - FBE;   // 14
constexpr int FBS3 = L3 - FBE;   // 13
constexpr int NPAT2 = 1 << FBS2; // 16384
constexpr int NPAT3 = 1 << FBS3; // 8192

typedef float v2f __attribute__((ext_vector_type(2)));

// ---- ws layout (float indices) ----
constexpr int OFF_T      = 0;                               // T[2][22][P] = 88
constexpr int OFF_SUMS   = OFF_T + 2 * 22 * P;
constexpr int SUMS_STRIDE = 96;
constexpr int OFF_PCHAIN = OFF_SUMS + NSTEPS * SUMS_STRIDE;
constexpr int OFF_KEYB   = OFF_PCHAIN + 40;
constexpr int OFF_CT     = OFF_KEYB + 128;
constexpr int OFF_CB     = OFF_CT + 32;
constexpr int OFF_NEED   = OFF_CB + 32;
constexpr int OFF_ZEND   = OFF_NEED + 8;                    // zero range end
constexpr int OFF_PAT2   = OFF_ZEND;                        // uint[16384]
constexpr int OFF_PAT3   = OFF_PAT2 + NPAT2;                // uint[8192]

constexpr float K2E = 2.8853900817779268f;   // 2*log2(e)
constexpr float KE  = 1.4426950408889634f;   // log2(e)

constexpr float CP0 = 0.85355339059f, CP1 = 0.14644660941f; // 2-node Chebyshev on (0,1)

struct Binom { unsigned v[22][22]; };
constexpr Binom make_binom() {
  Binom b{};
  for (int n = 0; n < 22; n++) {
    b.v[n][0] = 1;
    for (int k = 1; k < 22; k++)
      b.v[n][k] = (k > n) ? 0u : (k == n ? 1u : b.v[n - 1][k - 1] + b.v[n - 1][k]);
  }
  return b;
}
__device__ constexpr Binom BN = make_binom();

DEV float fast_tanh(float x) {
  float e = exp2f(x * K2E);
  return 1.0f - 2.0f * __builtin_amdgcn_rcpf(e + 1.0f);
}
DEV float fast_exp(float x) { return exp2f(x * KE); }
DEV void gatomic(float* p, float v) { unsafeAtomicAdd(p, v); }

DEV unsigned gosper(unsigned cmb) {
  unsigned u = cmb & (~cmb + 1u);
  unsigned v = cmb + u;
  return v | ((cmb ^ v) >> (1 + __ffs(u)));
}

// wave64 sum via DPP (VALU-only; LLVM AtomicOptimizer sequence). Total lands in lane 63.
DEV float dppsum64(float x) {
  float f = x;
  f += __int_as_float(__builtin_amdgcn_update_dpp(0, __float_as_int(f), 0x111, 0xf, 0xf, false));
  f += __int_as_float(__builtin_amdgcn_update_dpp(0, __float_as_int(f), 0x112, 0xf, 0xf, false));
  f += __int_as_float(__builtin_amdgcn_update_dpp(0, __float_as_int(f), 0x114, 0xf, 0xf, false));
  f += __int_as_float(__builtin_amdgcn_update_dpp(0, __float_as_int(f), 0x118, 0xf, 0xf, false));
  f += __int_as_float(__builtin_amdgcn_update_dpp(0, __float_as_int(f), 0x142, 0xa, 0xf, false));
  f += __int_as_float(__builtin_amdgcn_update_dpp(0, __float_as_int(f), 0x143, 0xc, 0xf, false));
  return f;   // valid in lane 63 of the wave
}

// =================== Kernel Z: init + popc-sorted pattern tables ===================
__global__ void kz(const float* p0, const float* sel,
                   const float* W1_2, const float* b1_2,
                   const float* W1_3, const float* b1_3, float* ws) {
  int tx = threadIdx.x;
  if (blockIdx.x == 0) {
    for (int i = tx; i < OFF_ZEND; i += blockDim.x) ws[i] = 0.0f;
    __syncthreads();
    if (tx < NSTEPS) {
      int t = tx;
      int g = (t < NSTEP2) ? 0 : 1;
      int L = g ? L3 : L2;
      const float* sbase = sel + (g ? (NSTEP2 * L2 + (t - NSTEP2) * L3) : t * L2);
      unsigned cb = 0; int c = 0;
      for (int d = 0; d < L; d++)
        if (sbase[d] > 0.5f) { cb |= 1u << d; c++; }
      ((int*)ws)[OFF_CT + t] = c;
      ((unsigned*)ws)[OFF_CB + t] = cb;
      atomicOr(&((unsigned*)ws)[OFF_NEED + g], 1u << c);
      const float* W1 = g ? W1_3 : W1_2;
      const float* b1 = g ? b1_3 : b1_2;
      for (int h = 0; h < 4; h++) {
        float s = b1[h];
        for (int d = 0; d < L; d++)
          if ((cb >> d) & 1) s += W1[h * (L + 1) + 1 + d];
        ws[OFF_KEYB + t * 4 + h] = s;
      }
      if (tx == 0) ws[OFF_PCHAIN] = p0[0];
    }
  } else {
    int r = (blockIdx.x - 1) * 256 + tx;   // 0..24575
    int NB, rr, off;
    if (r < NPAT2) { NB = FBS2; rr = r; off = OFF_PAT2; }
    else           { NB = FBS3; rr = r - NPAT2; off = OFF_PAT3; }
    int k = 0; unsigned base = 0;
    for (int kk = 0; kk <= NB; kk++) {
      unsigned sz = BN.v[NB][kk];
      if ((unsigned)rr < base + sz) { k = kk; break; }
      base += sz;
    }
    unsigned local = (unsigned)rr - base;
    unsigned pat = 0; int kk = k;
    for (int bb = NB - 1; bb >= 0 && kk > 0; bb--) {
      unsigned cnt = BN.v[bb][kk];
      if (local >= cnt) { pat |= 1u << bb; local -= cnt; kk--; }
    }
    ((unsigned*)ws)[off + rr] = pat;
  }
}

// =================== shared tab builder ===================
template<int LL>
DEV void build_tabs(const float* W1, float4 add,
                    float4* tabEX, float4* tabS0, float4* tabS1) {
  constexpr int NS1 = 1 << (LL - 14);
  int tx = threadIdx.x;
  for (int i = tx; i < 256 + NS1; i += 256) {
    if (i < 128) {
      int e = i;
      float s0 = 0, s1 = 0, s2 = 0, s3 = 0;
      for (int j = 0; j < 7; j++) if ((e >> j) & 1) {
        s0 += W1[0 * (LL + 1) + 1 + j]; s1 += W1[1 * (LL + 1) + 1 + j];
        s2 += W1[2 * (LL + 1) + 1 + j]; s3 += W1[3 * (LL + 1) + 1 + j];
      }
      tabEX[e] = make_float4(exp2f(K2E * s0), exp2f(K2E * s1), exp2f(K2E * s2), exp2f(K2E * s3));
    } else if (i < 256) {
      int e = i - 128;
      float s0 = add.x, s1 = add.y, s2 = add.z, s3 = add.w;
      for (int j = 0; j < 7; j++) if ((e >> j) & 1) {
        s0 += W1[0 * (LL + 1) + 1 + 7 + j]; s1 += W1[1 * (LL + 1) + 1 + 7 + j];
        s2 += W1[2 * (LL + 1) + 1 + 7 + j]; s3 += W1[3 * (LL + 1) + 1 + 7 + j];
      }
      tabS0[e] = make_float4(s0, s1, s2, s3);
    } else {
      int e = i - 256;
      float s0 = 0, s1 = 0, s2 = 0, s3 = 0;
      for (int j = 0; j < LL - 14; j++) if ((e >> j) & 1) {
        s0 += W1[0 * (LL + 1) + 1 + 14 + j]; s1 += W1[1 * (LL + 1) + 1 + 14 + j];
        s2 += W1[2 * (LL + 1) + 1 + 14 + j]; s3 += W1[3 * (LL + 1) + 1 + 14 + j];
      }
      tabS1[e] = make_float4(s0, s1, s2, s3);
    }
  }
}

// =================== Kernel A: per-class tabulation of T[g][c][j] ===================
constexpr int KA_B2 = NPAT2 / 256;  // 64
constexpr int KA_B3 = NPAT3 / 256;  // 32
constexpr int KA_BLOCKS = 22 * KA_B2 + 21 * KA_B3;  // 2080

template<int LL>
DEV void ka_work(int g, int c, int sub,
                 const float* W1, const float* b1, const float* W2, const float* b2,
                 float* ws, float4* tabEX, float4* tabS0, float4* tabS1, float* sT) {
  int tx = threadIdx.x;
  const unsigned* pats = ((const unsigned*)ws) + (LL == 21 ? OFF_PAT2 : OFF_PAT3);
  // popc-range early exit (patterns sorted by popc ascending)
  int pcFirst = __popc(pats[sub * 256]);
  int pcLast  = __popc(pats[sub * 256 + 255]);
  if (c < pcFirst || c - pcLast > FBE) return;
  float4 add = make_float4(b1[0], b1[1], b1[2], b1[3]);
  build_tabs<LL>(W1, add, tabEX, tabS0, tabS1);
  if (tx < P) sT[tx] = 0.0f;
  __syncthreads();
  unsigned pat = pats[sub * 256 + tx];
  int ce = c - __popc(pat);
  int trip = (ce >= 0 && ce <= FBE) ? (int)BN.v[FBE][ce] : 0;
  float4 vS0 = tabS0[pat & 127];
  float4 vS1 = tabS1[pat >> 7];
  float E0 = exp2f(K2E * (vS0.x + vS1.x));
  float E1 = exp2f(K2E * (vS0.y + vS1.y));
  float E2 = exp2f(K2E * (vS0.z + vS1.z));
  float E3 = exp2f(K2E * (vS0.w + vS1.w));
  float a0 = W1[0], a1 = W1[LL + 1], a2 = W1[2 * (LL + 1)], a3 = W1[3 * (LL + 1)];
  float w0 = W2[0], w1 = W2[1], w2 = W2[2], w3 = W2[3];
  float W0 = b2[0] + w0 + w1 + w2 + w3;
  float m0 = -2.0f * w0, m1 = -2.0f * w1, m2 = -2.0f * w2, m3 = -2.0f * w3;
  float EA00 = E0 * exp2f(K2E * CP0 * a0), EA01 = E1 * exp2f(K2E * CP0 * a1);
  float EA02 = E2 * exp2f(K2E * CP0 * a2), EA03 = E3 * exp2f(K2E * CP0 * a3);
  float EA10 = E0 * exp2f(K2E * CP1 * a0), EA11 = E1 * exp2f(K2E * CP1 * a1);
  float EA12 = E2 * exp2f(K2E * CP1 * a2), EA13 = E3 * exp2f(K2E * CP1 * a3);
  float acc0 = 0.0f, acc1 = 0.0f;
  unsigned iv = (trip > 0) ? ((1u << ce) - 1u) : 0u;
#pragma unroll 1
  for (int k = 0; k < trip; k++) {
    float4 tE = tabEX[iv];
    float o0 = W0, o1 = W0, rr;
    rr = __builtin_amdgcn_rcpf(fmaf(tE.x, EA00, 1.0f)); o0 = fmaf(m0, rr, o0);
    rr = __builtin_amdgcn_rcpf(fmaf(tE.y, EA01, 1.0f)); o0 = fmaf(m1, rr, o0);
    rr = __builtin_amdgcn_rcpf(fmaf(tE.z, EA02, 1.0f)); o0 = fmaf(m2, rr, o0);
    rr = __builtin_amdgcn_rcpf(fmaf(tE.w, EA03, 1.0f)); o0 = fmaf(m3, rr, o0);
    rr = __builtin_amdgcn_rcpf(fmaf(tE.x, EA10, 1.0f)); o1 = fmaf(m0, rr, o1);
    rr = __builtin_amdgcn_rcpf(fmaf(tE.y, EA11, 1.0f)); o1 = fmaf(m1, rr, o1);
    rr = __builtin_amdgcn_rcpf(fmaf(tE.z, EA12, 1.0f)); o1 = fmaf(m2, rr, o1);
    rr = __builtin_amdgcn_rcpf(fmaf(tE.w, EA13, 1.0f)); o1 = fmaf(m3, rr, o1);
    acc0 += exp2f(KE * o0);
    acc1 += exp2f(KE * o1);
    iv = gosper(iv);
  }
  float v0 = dppsum64(acc0), v1 = dppsum64(acc1);
  if ((tx & 63) == 63) {
    if (v0 != 0.0f) atomicAdd(&sT[0], v0);
    if (v1 != 0.0f) atomicAdd(&sT[1], v1);
  }
  __syncthreads();
  if (tx < P) {
    float v = sT[tx];
    if (v != 0.0f) gatomic(&ws[OFF_T + (g * 22 + c) * P + tx], v);
  }
}

__global__ __launch_bounds__(256) void ka(
    const float* W1_2, const float* b1_2, const float* W2_2, const float* b2_2,
    const float* W1_3, const float* b1_3, const float* W2_3, const float* b2_3,
    float* ws) {
  __shared__ float4 tabEX[128], tabS0[128], tabS1[128];
  __shared__ float sT[P];
  int b = blockIdx.x;
  int g, c, sub;
  if (b < 22 * KA_B2) { g = 0; c = b / KA_B2; sub = b % KA_B2; }
  else { int b3 = b - 22 * KA_B2; g = 1; c = b3 / KA_B3; sub = b3 % KA_B3; }
  unsigned need = ((const unsigned*)ws)[OFF_NEED + g];
  if (!((need >> c) & 1)) return;
  if (g == 0) ka_work<21>(0, c, sub, W1_2, b1_2, W2_2, b2_2, ws, tabEX, tabS0, tabS1, sT);
  else        ka_work<20>(1, c, sub, W1_3, b1_3, W2_3, b2_3, ws, tabEX, tabS0, tabS1, sT);
}

// =================== Kernel B: prob chain, 64-lane cooperative ===================
__global__ __launch_bounds__(64) void kb(const float* p0in,
                   const float* W1_2, const float* b1_2, const float* W2_2, const float* b2_2,
                   const float* W1_3, const float* b1_3, const float* W2_3, const float* b2_3,
                   float* ws, float* out) {
  __shared__ float sT[2 * 22 * P];
  __shared__ float sKEYB[128], sW1c0[8], sW2[8], sB2[2];
  __shared__ int sCT[32];
  int lane = threadIdx.x;
  for (int i = lane; i < 2 * 22 * P; i += 64) sT[i] = ws[OFF_T + i];
  for (int i = lane; i < 128; i += 64) sKEYB[i] = ws[OFF_KEYB + i];
  if (lane < 32) sCT[lane] = ((const int*)ws)[OFF_CT + lane];
  if (lane < 4) {
    sW1c0[lane]     = W1_2[lane * (L2 + 1)];
    sW1c0[4 + lane] = W1_3[lane * (L3 + 1)];
    sW2[lane]     = W2_2[lane];
    sW2[4 + lane] = W2_3[lane];
  }
  if (lane == 0) { sB2[0] = b2_2[0]; sB2[1] = b2_3[0]; }
  __syncthreads();
  float p = p0in[0];
  if (lane == 0) out[0] = p;
  int h = lane & 3;
#pragma unroll 1
  for (int tt = 0; tt < NSTEPS; tt++) {
    int g = (tt < NSTEP2) ? 0 : 1;
    int c = sCT[tt];
    float hk = fast_tanh(sKEYB[tt * 4 + h] + p * sW1c0[g * 4 + h]);
    float contrib = sW2[g * 4 + h] * hk;
    contrib += __shfl_xor(contrib, 1);
    contrib += __shfl_xor(contrib, 2);
    float outk = sB2[g] + contrib;
    float T0 = sT[(g * 22 + c) * P + 0], T1 = sT[(g * 22 + c) * P + 1];
    float d0 = p - CP0; if (fabsf(d0) < 1e-9f) d0 = (d0 < 0.0f) ? -1e-9f : 1e-9f;
    float d1 = p - CP1; if (fabsf(d1) < 1e-9f) d1 = (d1 < 0.0f) ? -1e-9f : 1e-9f;
    float q0 = 1.0f / d0, q1 = -1.0f / d1;
    float Se = (q0 * T0 + q1 * T1) / (q0 + q1);
    p = fast_exp(outk) / Se;
    if (lane == 0) { out[1 + tt] = p; ws[OFF_PCHAIN + 1 + tt] = p; }
  }
}

// =================== Kernel C: popc-sorted structural enumeration ===================
constexpr int KC_B2 = NPAT2 / 256;   // 64 blocks/step (g2)
constexpr int KC_B3 = NPAT3 / 256;   // 32 blocks/step (g3)
constexpr int KC_BLOCKS = NSTEP2 * KC_B2 + NSTEP3 * KC_B3;  // 1344

template<int LL>
DEV void kc_work(int t, int sub,
                 const float* W1, const float* b1, const float* W2, const float* b2,
                 float* ws, float4* tabEX, float4* tabS0, float4* tabS1, float* sS) {
  constexpr int FS = LL - FBE;   // structural bit count: 14 / 13
  int tx = threadIdx.x;
  int c = ((const int*)ws)[OFF_CT + t];
  const unsigned* pats = ((const unsigned*)ws) + (LL == 21 ? OFF_PAT2 : OFF_PAT3);
  // popc-range early exit (patterns sorted by popc ascending)
  int pcFirst = __popc(pats[sub * 256]);
  int pcLast  = __popc(pats[sub * 256 + 255]);
  if (c < pcFirst || c - pcLast > FBE) return;
  float p = ws[OFF_PCHAIN + t];
  float4 add = make_float4(b1[0] + p * W1[0 * (LL + 1)], b1[1] + p * W1[1 * (LL + 1)],
                           b1[2] + p * W1[2 * (LL + 1)], b1[3] + p * W1[3 * (LL + 1)]);
  build_tabs<LL>(W1, add, tabEX, tabS0, tabS1);
  if (tx < SUMS_STRIDE) sS[tx] = 0.0f;
  __syncthreads();
  unsigned pat = pats[sub * 256 + tx];
  int ce = c - __popc(pat);
  int trip = (ce >= 0 && ce <= FBE) ? (int)BN.v[FBE][ce] : 0;
  float4 vS0 = tabS0[pat & 127];
  float4 vS1 = tabS1[pat >> 7];
  float EbS0 = exp2f(K2E * (vS0.x + vS1.x));
  float EbS1 = exp2f(K2E * (vS0.y + vS1.y));
  float EbS2 = exp2f(K2E * (vS0.z + vS1.z));
  float EbS3 = exp2f(K2E * (vS0.w + vS1.w));
  float w0 = W2[0], w1 = W2[1], w2 = W2[2], w3 = W2[3];
  float b2s = b2[0];

  float aE = 0.0f, aW = 0.0f;
  v2f aQa = {0, 0}, aQb = {0, 0}, aWHa = {0, 0}, aWHb = {0, 0};
#define G_DECL(k) v2f g##k##a = {0, 0}, g##k##b = {0, 0};
  G_DECL(0) G_DECL(1) G_DECL(2) G_DECL(3) G_DECL(4) G_DECL(5) G_DECL(6)
#undef G_DECL

  unsigned iv = (trip > 0) ? ((1u << ce) - 1u) : 0u;
#pragma unroll 1
  for (int k = 0; k < trip; k++) {
    float4 tE = tabEX[iv];   // iv wave-uniform -> broadcast read
    float r0 = __builtin_amdgcn_rcpf(fmaf(tE.x, EbS0, 1.0f));
    float r1 = __builtin_amdgcn_rcpf(fmaf(tE.y, EbS1, 1.0f));
    float r2 = __builtin_amdgcn_rcpf(fmaf(tE.z, EbS2, 1.0f));
    float r3 = __builtin_amdgcn_rcpf(fmaf(tE.w, EbS3, 1.0f));
    float t0 = fmaf(-2.0f, r0, 1.0f);
    float t1 = fmaf(-2.0f, r1, 1.0f);
    float t2 = fmaf(-2.0f, r2, 1.0f);
    float t3 = fmaf(-2.0f, r3, 1.0f);
    float outv = b2s + w0 * t0 + w1 * t1 + w2 * t2 + w3 * t3;
    float e = fast_exp(outv);
    float q0 = outv * (1.0f - t0 * t0) * w0;
    float q1 = outv * (1.0f - t1 * t1) * w1;
    float q2 = outv * (1.0f - t2 * t2) * w2;
    float q3 = outv * (1.0f - t3 * t3) * w3;
    v2f qa = {q0, q1}, qb = {q2, q3};
    aE += e; aW += outv;
    aQa += qa; aQb += qb;
    v2f ov = {outv, outv};
    v2f ta = {t0, t1}, tb = {t2, t3};
    aWHa += ov * ta; aWHb += ov * tb;
#define G_UPD(k) { float bd = (float)((iv >> k) & 1u); v2f bdv = {bd, bd}; \
    g##k##a += bdv * qa; g##k##b += bdv * qb; }
    G_UPD(0) G_UPD(1) G_UPD(2) G_UPD(3) G_UPD(4) G_UPD(5) G_UPD(6)
#undef G_UPD
    iv = gosper(iv);
  }

  // ---- epilogue (DPP reductions, lane 63 holds totals) ----
  int lane = tx & 63;
  float rr;
  rr = dppsum64(aE); if (lane == 63 && rr != 0.0f) atomicAdd(&sS[0], rr);
  rr = dppsum64(aW); if (lane == 63 && rr != 0.0f) atomicAdd(&sS[1], rr);
  rr = dppsum64(aQa.x); if (lane == 63 && rr != 0.0f) atomicAdd(&sS[2], rr);
  rr = dppsum64(aQa.y); if (lane == 63 && rr != 0.0f) atomicAdd(&sS[3], rr);
  rr = dppsum64(aQb.x); if (lane == 63 && rr != 0.0f) atomicAdd(&sS[4], rr);
  rr = dppsum64(aQb.y); if (lane == 63 && rr != 0.0f) atomicAdd(&sS[5], rr);
  rr = dppsum64(aWHa.x); if (lane == 63 && rr != 0.0f) atomicAdd(&sS[6], rr);
  rr = dppsum64(aWHa.y); if (lane == 63 && rr != 0.0f) atomicAdd(&sS[7], rr);
  rr = dppsum64(aWHb.x); if (lane == 63 && rr != 0.0f) atomicAdd(&sS[8], rr);
  rr = dppsum64(aWHb.y); if (lane == 63 && rr != 0.0f) atomicAdd(&sS[9], rr);
  // enumerated bits d = 0..6
#define GF(k) { \
    rr = dppsum64(g##k##a.x); if (lane == 63 && rr != 0.0f) atomicAdd(&sS[10 + 0 * 21 + k], rr); \
    rr = dppsum64(g##k##a.y); if (lane == 63 && rr != 0.0f) atomicAdd(&sS[10 + 1 * 21 + k], rr); \
    rr = dppsum64(g##k##b.x); if (lane == 63 && rr != 0.0f) atomicAdd(&sS[10 + 2 * 21 + k], rr); \
    rr = dppsum64(g##k##b.y); if (lane == 63 && rr != 0.0f) atomicAdd(&sS[10 + 3 * 21 + k], rr); }
  GF(0) GF(1) GF(2) GF(3) GF(4) GF(5) GF(6)
#undef GF
  // structural bits d = FBE + j, via per-lane mask of the pattern
#pragma unroll
  for (int j = 0; j < 14; j++) {
    if (j < FS) {
      float m = (float)((pat >> j) & 1u);
      rr = dppsum64(m * aQa.x); if (lane == 63 && rr != 0.0f) atomicAdd(&sS[10 + 0 * 21 + FBE + j], rr);
      rr = dppsum64(m * aQa.y); if (lane == 63 && rr != 0.0f) atomicAdd(&sS[10 + 1 * 21 + FBE + j], rr);
      rr = dppsum64(m * aQb.x); if (lane == 63 && rr != 0.0f) atomicAdd(&sS[10 + 2 * 21 + FBE + j], rr);
      rr = dppsum64(m * aQb.y); if (lane == 63 && rr != 0.0f) atomicAdd(&sS[10 + 3 * 21 + FBE + j], rr);
    }
  }
  __syncthreads();
  if (tx < SUMS_STRIDE) {
    float v = sS[tx];
    if (v != 0.0f) gatomic(&ws[OFF_SUMS + t * SUMS_STRIDE + tx], v);
  }
}

__global__ __launch_bounds__(256) void kc(
    const float* W1_2, const float* b1_2, const float* W2_2, const float* b2_2,
    const float* W1_3, const float* b1_3, const float* W2_3, const float* b2_3,
    float* ws) {
  __shared__ float4 tabEX[128], tabS0[128], tabS1[128];
  __shared__ float sS[SUMS_STRIDE];
  int b = blockIdx.x;
  if (b < NSTEP2 * KC_B2) {
    int t = b / KC_B2, sub = b % KC_B2;
    kc_work<21>(t, sub, W1_2, b1_2, W2_2, b2_2, ws, tabEX, tabS0, tabS1, sS);
  } else {
    int b3 = b - NSTEP2 * KC_B2;
    int t = NSTEP2 + b3 / KC_B3, sub = b3 % KC_B3;
    kc_work<20>(t, sub, W1_3, b1_3, W2_3, b2_3, ws, tabEX, tabS0, tabS1, sS);
  }
}

// =================== Kernel D: finalize gradient outputs ===================
__global__ __launch_bounds__(256) void kd(
                   const float* W1_2, const float* b1_2, const float* W2_2, const float* b2_2,
                   const float* W1_3, const float* b1_3, const float* W2_3, const float* b2_3,
                   const float* ws, float* out) {
  __shared__ float sS[NSTEPS * SUMS_STRIDE];
  __shared__ float sk_s[NSTEPS][4], hk_s[NSTEPS][4], pp_s[NSTEPS], s0i_s[NSTEPS];
  int tx = threadIdx.x;
  for (int i = tx; i < NSTEPS * SUMS_STRIDE; i += 256) sS[i] = ws[OFF_SUMS + i];
  __syncthreads();
  if (tx < NSTEPS) {
    int t = tx; int g = (t < NSTEP2) ? 0 : 1; int L = g ? L3 : L2;
    const float* W1 = g ? W1_3 : W1_2;
    const float* W2 = g ? W2_3 : W2_2;
    float p = ws[OFF_PCHAIN + t];
    pp_s[t] = p;
    s0i_s[t] = 1.0f / sS[t * SUMS_STRIDE + 0];
    for (int h = 0; h < 4; h++) {
      float hk = fast_tanh(ws[OFF_KEYB + t * 4 + h] + p * W1[h * (L + 1)]);
      hk_s[t][h] = hk;
      sk_s[t][h] = (1.0f - hk * hk) * W2[h];
    }
  }
  __syncthreads();
  const unsigned* cbp = (const unsigned*)ws;
  for (int o = 33 + tx; o < 223; o += blockDim.x) {
    float val = 0.0f;
    if (o < 130) {
      if (o < 121) {
        int e = o - 33; int h = e / 22, d = e % 22;
        for (int t = 0; t < NSTEP2; t++) {
          float xk = (d == 0) ? pp_s[t] : (float)((cbp[OFF_CB + t] >> (d - 1)) & 1);
          float gs = (d == 0) ? pp_s[t] * sS[t * SUMS_STRIDE + 2 + h]
                              : sS[t * SUMS_STRIDE + 10 + h * 21 + (d - 1)];
          val += sk_s[t][h] * xk - gs * s0i_s[t];
        }
      } else if (o < 125) { int h = o - 121;
        for (int t = 0; t < NSTEP2; t++) val += sk_s[t][h] - sS[t * SUMS_STRIDE + 2 + h] * s0i_s[t];
      } else if (o < 129) { int h = o - 125;
        for (int t = 0; t < NSTEP2; t++) val += hk_s[t][h] - sS[t * SUMS_STRIDE + 6 + h] * s0i_s[t];
      } else {
        for (int t = 0; t < NSTEP2; t++) val += 1.0f - sS[t * SUMS_STRIDE + 1] * s0i_s[t];
      }
    } else {
      if (o < 214) {
        int e = o - 130; int h = e / 21, d = e % 21;
        for (int t = NSTEP2; t < NSTEPS; t++) {
          float xk = (d == 0) ? pp_s[t] : (float)((cbp[OFF_CB + t] >> (d - 1)) & 1);
          float gs = (d == 0) ? pp_s[t] * sS[t * SUMS_STRIDE + 2 + h]
                              : sS[t * SUMS_STRIDE + 10 + h * 21 + (d - 1)];
          val += sk_s[t][h] * xk - gs * s0i_s[t];
        }
      } else if (o < 218) { int h = o - 214;
        for (int t = NSTEP2; t < NSTEPS; t++) val += sk_s[t][h] - sS[t * SUMS_STRIDE + 2 + h] * s0i_s[t];
      } else if (o < 222) { int h = o - 218;
        for (int t = NSTEP2; t < NSTEPS; t++) val += hk_s[t][h] - sS[t * SUMS_STRIDE + 6 + h] * s0i_s[t];
      } else {
        for (int t = NSTEP2; t < NSTEPS; t++) val += 1.0f - sS[t * SUMS_STRIDE + 1] * s0i_s[t];
      }
    }
    out[o] = val;
  }
}

extern "C" void kernel_launch(void* const* d_in, const int* in_sizes, int n_in,
                              void* d_out, int out_size, void* d_ws, size_t ws_size,
                              hipStream_t stream) {
  const float* p0   = (const float*)d_in[0];
  const float* sel  = (const float*)d_in[1];
  const float* W1_2 = (const float*)d_in[2]; const float* b1_2 = (const float*)d_in[3];
  const float* W2_2 = (const float*)d_in[4]; const float* b2_2 = (const float*)d_in[5];
  const float* W1_3 = (const float*)d_in[6]; const float* b1_3 = (const float*)d_in[7];
  const float* W2_3 = (const float*)d_in[8]; const float* b2_3 = (const float*)d_in[9];
  float* out = (float*)d_out;
  float* ws  = (float*)d_ws;
  hipLaunchKernelGGL(kz, dim3(1 + (NPAT2 + NPAT3) / 256), dim3(256), 0, stream,
                     p0, sel, W1_2, b1_2, W1_3, b1_3, ws);
  hipLaunchKernelGGL(ka, dim3(KA_BLOCKS), dim3(256), 0, stream,
                     W1_2, b1_2, W2_2, b2_2, W1_3, b1_3, W2_3, b2_3, ws);
  hipLaunchKernelGGL(kb, dim3(1), dim3(64), 0, stream, p0,
                     W1_2, b1_2, W2_2, b2_2, W1_3, b1_3, W2_3, b2_3, ws, out);
  hipLaunchKernelGGL(kc, dim3(KC_BLOCKS), dim3(256), 0, stream,
                     W1_2, b1_2, W2_2, b2_2, W1_3, b1_3, W2_3, b2_3, ws);
  hipLaunchKernelGGL(kd, dim3(1), dim3(256), 0, stream,
                     W1_2, b1_2, W2_2, b2_2, W1_3, b1_3, W2_3, b2_3, ws, out);
}